// Round 4
// baseline (556.648 us; speedup 1.0000x reference)
//
#include <hip/hip_runtime.h>

// ROI Align (max) — R7: 8-tile pipelined channel loop, cohort dispatch.
//
// R6 post-mortem: FETCH fell 304->234 MB but dur stayed ~99 us and BW fell
// to 2.7 TB/s -> stall-bound, not byte-bound. Each block was one staging
// burst + barrier + tiny compute; latency never hidden.
// R7: block = (box, cg-octet) = 8 consecutive 4-channel tiles, R4's proven
// single-buffer prefetch loop (ds_write j -> issue loads j+1 -> barrier ->
// compute j -> barrier). R4 sustained 3.8 TB/s / VALU 3% with this loop; its
// failures (XCD-chunked channels, NT stores) are NOT repeated: dispatch is
// cohort-ordered (bid = cgo*512 + n -> box n always on XCD n%8, each box's
// rows fetched by exactly one XCD), stores are plain.
// Dynamic span staging (lane16 < nl4) and cooperative rowoffs kept from R6.
// No precompute table: per-block fixed cost amortizes over 8 tiles.
//
// feature: (2, 256, 200, 304) fp32; boxes: (512,4); batch_idx: (512,) i32
// out: (512, 256, 7, 7) fp32. SPATIAL_SCALE=0.25, POOLED=7, SR=2, MODE=max.

#define SPATIAL_SCALE 0.25f
#define POOLED 7
#define SR 2

constexpr int Cc = 256;
constexpr int Hc = 200;
constexpr int Wc = 304;
constexpr int Nc = 512;

constexpr int CG      = 4;               // channels per tile
constexpr int TILES   = 8;               // tiles per block (32 consecutive ch)
constexpr int NSAMP   = POOLED * SR;     // 14 sample coords per axis
constexpr int NROW    = NSAMP * 2;       // 28 row slots (y0 0..13, y1 14..27)
constexpr int XPAD    = 60;              // LDS row stride (writes <= 56 cols)
constexpr int CH_STR  = NROW * XPAD;     // 1680 floats per channel
constexpr int CELLS   = POOLED * POOLED; // 49
constexpr int OUTS    = CG * CELLS;      // 196 outputs per tile
constexpr int PER_BOX = Cc * CELLS;      // 12544
constexpr int PLANE   = Hc * Wc;         // 60800
constexpr int A1_OFF  = NSAMP * XPAD;    // y1 block offset within channel

__global__ __launch_bounds__(256) void roi_align_max_kernel(
    const float* __restrict__ feature,
    const float* __restrict__ boxes,
    const int*   __restrict__ batch_idx,
    float*       __restrict__ out)
{
    __shared__ float lds[CG * CH_STR];   // 26,880 B -> 6 blocks/CU
    __shared__ int   rowoff_sh[NROW];

    const int bid = blockIdx.x;
    const int cgo = bid >> 9;            // cg-octet 0..7 (cohort-outer)
    const int n   = bid & (Nc - 1);      // box; XCD = n % 8 for all cgo
    const int tid = threadIdx.x;

    // ---- box math (block-uniform -> scalar) ----
    const float rsx = boxes[n * 4 + 0] * SPATIAL_SCALE;
    const float rsy = boxes[n * 4 + 1] * SPATIAL_SCALE;
    const float rex = boxes[n * 4 + 2] * SPATIAL_SCALE;
    const float rey = boxes[n * 4 + 3] * SPATIAL_SCALE;
    const float roi_w = fmaxf(rex - rsx, 1.0f);
    const float roi_h = fmaxf(rey - rsy, 1.0f);
    const float bin_w = roi_w / (float)POOLED;
    const float bin_h = roi_h / (float)POOLED;
    const int   b     = batch_idx[n];

    const float x_first = __fadd_rn(rsx, __fmul_rn(0.25f, bin_w));
    const float xc0     = fminf(fmaxf(x_first, 0.0f), (float)(Wc - 1));
    const int   xbase   = ((int)floorf(xc0)) & ~3;

    // dynamic span: last x sample (px = 6.75) is the monotone max.
    const float x_last = __fadd_rn(rsx, __fmul_rn(6.75f, bin_w));
    const float xlc    = fminf(fmaxf(x_last, 0.0f), (float)(Wc - 1));
    const int   x0l    = (int)floorf(xlc);
    const int   xlastc = min(x0l + 1, Wc - 1);
    const int   span   = xlastc - xbase + 1;      // <= 54
    const int   nl4    = (span + 4) >> 2;         // +guard; <= 14 float4 lanes

    // ---- cooperative row offsets (28 threads) ----
    if (tid < NROW) {
        const int  which = tid >= NSAMP;
        const int  s     = which ? tid - NSAMP : tid;
        const float py   = fmaf((float)s, 0.5f, 0.25f);   // p + (sub+.5)/2 exact
        const float fy   = __fadd_rn(rsy, __fmul_rn(py, bin_h));
        const float fyc  = fminf(fmaxf(fy, 0.0f), (float)(Hc - 1));
        const int   y0   = (int)floorf(fyc);
        const int   row  = which ? min(y0 + 1, Hc - 1) : y0;
        rowoff_sh[tid] = row * Wc;
    }
    __syncthreads();

    // ---- staging setup + first tile's loads (issued ASAP) ----
    const int c_st   = tid >> 6;         // wave = channel within tile
    const int lane16 = tid & 15;
    const int rquad  = (tid >> 4) & 3;
    const int col    = min(xbase + lane16 * 4, Wc - 4);
    const bool act   = (lane16 < nl4);

    int ro[7];
    #pragma unroll
    for (int it = 0; it < 7; ++it)
        ro[it] = rowoff_sh[it * 4 + rquad];        // broadcast reads

    const float* __restrict__ gp =
        feature + ((size_t)b * Cc + (size_t)cgo * (CG * TILES) + c_st)
                * (size_t)PLANE;
    float4 st[7];
    if (act) {
        #pragma unroll
        for (int it = 0; it < 7; ++it)
            st[it] = *(const float4*)(gp + ro[it] + col);
    }
    const int lw = c_st * CH_STR + rquad * XPAD + lane16 * 4;

    // ---- per-thread compute metadata (overlaps first loads' latency) ----
    const int cellc = min(tid, OUTS - 1);
    const int c_cl  = cellc / CELLS;
    const int cell  = cellc - c_cl * CELLS;
    const int ph    = cell / POOLED;
    const int pw    = cell - ph * POOLED;

    float w00[2][2], w01[2][2], w10[2][2], w11[2][2];
    int   a0t[2][2];                     // absolute LDS float index of y0 tap
    #pragma unroll
    for (int sy = 0; sy < SR; ++sy) {
        const int   sY  = ph * SR + sy;
        const float py  = (float)ph + ((float)sy + 0.5f) * 0.5f;
        const float fy  = __fadd_rn(rsy, __fmul_rn(py, bin_h));
        const bool  vy  = (fy > -1.0f) && (fy < (float)Hc);
        const float fyc = fminf(fmaxf(fy, 0.0f), (float)(Hc - 1));
        const int   y0i = (int)floorf(fyc);
        const float ly  = fyc - (float)y0i;
        const float hy  = 1.0f - ly;
        #pragma unroll
        for (int sx = 0; sx < SR; ++sx) {
            const float px  = (float)pw + ((float)sx + 0.5f) * 0.5f;
            const float fx  = __fadd_rn(rsx, __fmul_rn(px, bin_w));
            const bool  vx  = (fx > -1.0f) && (fx < (float)Wc);
            const float fxc = fminf(fmaxf(fx, 0.0f), (float)(Wc - 1));
            const int   x0i = (int)floorf(fxc);
            const float lx  = fxc - (float)x0i;
            const float hx  = 1.0f - lx;
            const int   c0  = x0i - xbase;
            const bool  v   = vy && vx;      // validity folded into weights
            w00[sy][sx] = v ? hy * hx : 0.0f;
            w01[sy][sx] = v ? hy * lx : 0.0f;
            w10[sy][sx] = v ? ly * hx : 0.0f;
            w11[sy][sx] = v ? ly * lx : 0.0f;
            a0t[sy][sx] = c_cl * CH_STR + sY * XPAD + c0;
        }
    }
    float* __restrict__ outp = out + (size_t)n * PER_BOX
        + ((size_t)cgo * (CG * TILES) + c_cl) * CELLS + cell;

    // ---- pipelined tile loop: ds_write j, prefetch j+1, compute j ----
    #pragma unroll
    for (int j = 0; j < TILES; ++j) {
        if (act) {
            #pragma unroll
            for (int it = 0; it < 7; ++it)
                *(float4*)&lds[lw + it * (4 * XPAD)] = st[it];
            if (j + 1 < TILES) {
                gp += (size_t)CG * PLANE;           // next 4 channels
                #pragma unroll
                for (int it = 0; it < 7; ++it)
                    st[it] = *(const float4*)(gp + ro[it] + col);
            }
        }
        __syncthreads();                 // staging visible

        if (tid < OUTS) {
            float m = -INFINITY;
            #pragma unroll
            for (int sy = 0; sy < SR; ++sy) {
                #pragma unroll
                for (int sx = 0; sx < SR; ++sx) {
                    const int a0 = a0t[sy][sx];
                    const float bil = w00[sy][sx] * lds[a0]
                                    + w01[sy][sx] * lds[a0 + 1]
                                    + w10[sy][sx] * lds[a0 + A1_OFF]
                                    + w11[sy][sx] * lds[a0 + A1_OFF + 1];
                    m = fmaxf(m, bil);
                }
            }
            outp[j * OUTS] = m;          // plain store; imm offset
        }
        __syncthreads();                 // LDS reads done before next writes
    }
}

extern "C" void kernel_launch(void* const* d_in, const int* in_sizes, int n_in,
                              void* d_out, int out_size, void* d_ws, size_t ws_size,
                              hipStream_t stream) {
    const float* feature   = (const float*)d_in[0];
    const float* boxes     = (const float*)d_in[1];
    const int*   batch_idx = (const int*)d_in[2];
    float*       out       = (float*)d_out;

    const int grid = (Cc / (CG * TILES)) * Nc;   // 8 * 512 = 4096, cgo-outer
    roi_align_max_kernel<<<grid, 256, 0, stream>>>(feature, boxes,
                                                   batch_idx, out);
}